// Round 2
// baseline (526.847 us; speedup 1.0000x reference)
//
#include <hip/hip_runtime.h>
#include <math.h>

// Problem shape (fixed by reference setup_inputs)
#define BATCH 32
#define SEQ   4096
#define HID   768
#define HV4   (HID / 4)                      // 192 float4 per row
#define CHUNKS 64                            // chunks per batch
#define ROWS_PER_BLOCK (SEQ / CHUNKS)        // 64
#define NWAVES 4
#define ROWS_PER_WAVE (ROWS_PER_BLOCK / NWAVES) // 16
#define RING 4                               // wave-private row slots (3 KB each)

typedef __attribute__((ext_vector_type(4))) float f4v;

__device__ __forceinline__ float dot4(f4v a, f4v b) {
  return a.x * b.x + a.y * b.y + a.z * b.z + a.w * b.w;
}

// Async 16B/lane global->LDS DMA (fire-and-forget, tracked by vmcnt).
// LDS dst must be wave-uniform base + lane*16 -> our layout is linear.
__device__ __forceinline__ void async_copy16(const f4v* g, f4v* l) {
  __builtin_amdgcn_global_load_lds(
      (const __attribute__((address_space(1))) void*)g,
      (__attribute__((address_space(3))) void*)l,
      16, 0, 0);
}

// Stage one 3 KB row (3 x 1KB-per-wave DMA instructions).
__device__ __forceinline__ void stage_row(const f4v* gbase, f4v* ring,
                                          int row, int lane) {
  const f4v* g = gbase + (size_t)row * HV4;
  f4v* dst = ring + (row & (RING - 1)) * HV4;
  async_copy16(g + lane,       dst + lane);
  async_copy16(g + lane + 64,  dst + lane + 64);
  async_copy16(g + lane + 128, dst + lane + 128);
}

// vmcnt(N) with N constant after full unroll (asm needs an immediate).
__device__ __forceinline__ void vwait(int n) {
  switch (n) {
    case 0: asm volatile("s_waitcnt vmcnt(0)" ::: "memory"); break;
    case 3: asm volatile("s_waitcnt vmcnt(3)" ::: "memory"); break;
    case 6: asm volatile("s_waitcnt vmcnt(6)" ::: "memory"); break;
    default: asm volatile("s_waitcnt vmcnt(9)" ::: "memory"); break;
  }
}

// Pass 1: one block per (chunk, batch). Each wave is fully INDEPENDENT
// (zero barriers in the streaming loop): it streams its 16 rows through a
// wave-private 4-deep LDS ring via async global_load_lds. vmcnt(9) retires
// exactly the oldest row's 3 loads (vmcnt completes oldest-first), so 3 rows
// (9-12 KB) stay in flight per wave continuously -> HBM queue never drains.
// Online softmax per row; block combines 4 wave partials at the end.
__global__ __launch_bounds__(256, 3)
void attn_pass1(const float* __restrict__ hidden,
                const float* __restrict__ q,
                float* __restrict__ m_ws,
                float* __restrict__ l_ws,
                float* __restrict__ o_ws) {
  __shared__ float lds[NWAVES][RING * HID];  // 48 KB: 12 KB ring per wave
  __shared__ float s_m[NWAVES], s_l[NWAVES];

  const int chunk = blockIdx.x;
  const int b     = blockIdx.y;
  const int tid   = threadIdx.x;
  const int wave  = tid >> 6;
  const int lane  = tid & 63;

  // Query fragment for this lane: floats 4*lane.. , +256, +512
  const f4v* q4 = reinterpret_cast<const f4v*>(q);
  const f4v qa = q4[lane];
  const f4v qb = q4[lane + 64];
  const f4v qc = q4[lane + 128];

  const int row0 = chunk * ROWS_PER_BLOCK + wave * ROWS_PER_WAVE;
  const f4v* gbase = reinterpret_cast<const f4v*>(hidden)
                   + ((size_t)b * SEQ + (size_t)row0) * HV4;
  f4v* ring = reinterpret_cast<f4v*>(lds[wave]);

  // Prologue: stage rows 0..3 (12 DMA instructions outstanding)
  #pragma unroll
  for (int r = 0; r < RING; ++r) stage_row(gbase, ring, r, lane);

  float m = -INFINITY;
  float l = 0.0f;
  f4v oa = (f4v)0.0f;
  f4v ob = (f4v)0.0f;
  f4v oc = (f4v)0.0f;

  #pragma unroll
  for (int r = 0; r < ROWS_PER_WAVE; ++r) {
    // Retire exactly row r's loads; keep rows r+1..r+3 in flight.
    vwait(r <= 12 ? 9 : 3 * (15 - r));
    __builtin_amdgcn_sched_barrier(0);

    const f4v* rp = ring + (r & (RING - 1)) * HV4;
    const f4v a0 = rp[lane];
    const f4v b0 = rp[lane + 64];
    const f4v c0 = rp[lane + 128];

    // Slot is free once the 3 ds_reads retired into registers; refill it
    // immediately so the DMA flies under this row's compute.
    asm volatile("s_waitcnt lgkmcnt(0)" ::: "memory");
    __builtin_amdgcn_sched_barrier(0);
    if (r + RING < ROWS_PER_WAVE) stage_row(gbase, ring, r + RING, lane);

    float p = dot4(a0, qa) + dot4(b0, qb) + dot4(c0, qc);
    #pragma unroll
    for (int off = 32; off >= 1; off >>= 1)
      p += __shfl_xor(p, off, 64);

    if (p > m) {                        // wave-uniform branch
      const float s = __expf(m - p);    // exp(-inf)=0 on first row
      l *= s;
      oa *= s; ob *= s; oc *= s;
      m = p;
    }
    const float e = __expf(p - m);      // ==1 when this row is the new max
    l += e;
    oa += e * a0;
    ob += e * b0;
    oc += e * c0;
  }

  // Combine the 4 wave partials. Reuse lds[0] (exactly NWAVES*HID floats);
  // safe: barrier below guarantees all waves finished reading their rings.
  __syncthreads();
  float (*s_o)[HID] = reinterpret_cast<float(*)[HID]>(lds[0]);
  f4v* so4 = reinterpret_cast<f4v*>(s_o[wave]);
  so4[lane]       = oa;
  so4[lane + 64]  = ob;
  so4[lane + 128] = oc;
  if (lane == 0) { s_m[wave] = m; s_l[wave] = l; }
  __syncthreads();

  const float mb = fmaxf(fmaxf(s_m[0], s_m[1]), fmaxf(s_m[2], s_m[3]));
  const float w0 = __expf(s_m[0] - mb);
  const float w1 = __expf(s_m[1] - mb);
  const float w2 = __expf(s_m[2] - mb);
  const float w3 = __expf(s_m[3] - mb);
  const float lsum = w0 * s_l[0] + w1 * s_l[1] + w2 * s_l[2] + w3 * s_l[3];

  const int pidx = b * CHUNKS + chunk;
  float* O = o_ws + (size_t)pidx * HID;
  #pragma unroll
  for (int j = 0; j < 3; ++j) {
    const int h = tid + 256 * j;
    O[h] = w0 * s_o[0][h] + w1 * s_o[1][h] + w2 * s_o[2][h] + w3 * s_o[3][h];
  }
  if (tid == 0) { m_ws[pidx] = mb; l_ws[pidx] = lsum; }
}

// Pass 2: one thread per output element. grid (BATCH, 6) x 128 threads.
// m/l loads are redundant per thread but fully L2-resident (8 KB total).
__global__ __launch_bounds__(128)
void attn_pass2(const float* __restrict__ m_ws,
                const float* __restrict__ l_ws,
                const float* __restrict__ o_ws,
                float* __restrict__ out) {
  const int b = blockIdx.x;
  const int h = blockIdx.y * 128 + threadIdx.x;

  float mg = -INFINITY;
  #pragma unroll 8
  for (int c = 0; c < CHUNKS; ++c)
    mg = fmaxf(mg, m_ws[b * CHUNKS + c]);

  float L = 0.0f;
  float acc = 0.0f;
  #pragma unroll 8
  for (int c = 0; c < CHUNKS; ++c) {
    const int pi = b * CHUNKS + c;
    const float a = __expf(m_ws[pi] - mg);
    L += a * l_ws[pi];
    acc += a * o_ws[(size_t)pi * HID + h];
  }
  out[(size_t)b * HID + h] = acc / L;
}

extern "C" void kernel_launch(void* const* d_in, const int* in_sizes, int n_in,
                              void* d_out, int out_size, void* d_ws, size_t ws_size,
                              hipStream_t stream) {
  const float* hidden = (const float*)d_in[0];   // [32, 4096, 768] fp32
  const float* q      = (const float*)d_in[1];   // [1, 768] fp32
  float* out = (float*)d_out;                    // [32, 768] fp32

  // Workspace layout: m[2048] | l[2048] | O[2048*768]  (~6.3 MB total)
  float* m_ws = (float*)d_ws;
  float* l_ws = m_ws + BATCH * CHUNKS;
  float* o_ws = l_ws + BATCH * CHUNKS;

  dim3 grid1(CHUNKS, BATCH);
  attn_pass1<<<grid1, 256, 0, stream>>>(hidden, q, m_ws, l_ws, o_ws);
  dim3 grid2(BATCH, HID / 128);
  attn_pass2<<<grid2, 128, 0, stream>>>(m_ws, l_ws, o_ws, out);
}

// Round 3
// 494.760 us; speedup vs baseline: 1.0649x; 1.0649x over previous
//
#include <hip/hip_runtime.h>
#include <math.h>

// Problem shape (fixed by reference setup_inputs)
#define BATCH 32
#define SEQ   4096
#define HID   768
#define HV4   (HID / 4)                      // 192 float4 per row
#define CHUNKS 64                            // chunks per batch
#define ROWS_PER_BLOCK (SEQ / CHUNKS)        // 64
#define NWAVES 4
#define ROWS_PER_WAVE (ROWS_PER_BLOCK / NWAVES) // 16
#define RG 2                                 // rows per group
#define NG (ROWS_PER_WAVE / RG)              // 8 groups, fully unrolled

typedef __attribute__((ext_vector_type(4))) float f4v;

__device__ __forceinline__ float dot4(f4v a, f4v b) {
  return a.x * b.x + a.y * b.y + a.z * b.z + a.w * b.w;
}

// Pass 1: one block per (chunk, batch). Register double-buffer, prefetch
// distance 1: group g+1's 6 nontemporal loads are ISSUED before group g's
// compute, so the compiler's counted vmcnt keeps ~6 KB/wave in flight
// continuously (x16 waves/CU = 96 KB >> 9.2 KB BDP) instead of
// burst-load -> memory-silent-compute. No LDS staging (r1/r2 showed the
// global_load_lds round-trip costs +28 us on this kernel). Rows are read
// ONCE -> nontemporal to avoid polluting L2/L3.
__global__ __launch_bounds__(256, 4)
void attn_pass1(const float* __restrict__ hidden,
                const float* __restrict__ q,
                float* __restrict__ m_ws,
                float* __restrict__ l_ws,
                float* __restrict__ o_ws) {
  const int chunk = blockIdx.x;
  const int b     = blockIdx.y;
  const int tid   = threadIdx.x;
  const int wave  = tid >> 6;
  const int lane  = tid & 63;

  // Query fragment for this lane: floats 4*lane.. , +256, +512
  const f4v* q4 = reinterpret_cast<const f4v*>(q);
  const f4v qa = q4[lane];
  const f4v qb = q4[lane + 64];
  const f4v qc = q4[lane + 128];

  const int row0 = chunk * ROWS_PER_BLOCK + wave * ROWS_PER_WAVE;
  const f4v* base = reinterpret_cast<const f4v*>(hidden)
                  + ((size_t)b * SEQ + (size_t)row0) * HV4;

  // Two row-group buffers; all indices compile-time after full unroll
  // (runtime-indexed ext_vector arrays would go to scratch).
  f4v buf[2][RG][3];

  // Prologue: load group 0 into buf[0]
  #pragma unroll
  for (int r = 0; r < RG; ++r) {
    const f4v* rp = base + (size_t)r * HV4;
    buf[0][r][0] = __builtin_nontemporal_load(rp + lane);
    buf[0][r][1] = __builtin_nontemporal_load(rp + lane + 64);
    buf[0][r][2] = __builtin_nontemporal_load(rp + lane + 128);
  }

  float m = -INFINITY;
  float l = 0.0f;
  f4v oa = (f4v)0.0f;
  f4v ob = (f4v)0.0f;
  f4v oc = (f4v)0.0f;

  #pragma unroll
  for (int g = 0; g < NG; ++g) {
    const int cur = g & 1;
    const int nxt = cur ^ 1;

    // Issue next group's loads FIRST; first use of buf[cur] below then
    // waits with vmcnt(6) (these 6 still outstanding), not vmcnt(0).
    if (g + 1 < NG) {
      #pragma unroll
      for (int r = 0; r < RG; ++r) {
        const f4v* rp = base + (size_t)((g + 1) * RG + r) * HV4;
        buf[nxt][r][0] = __builtin_nontemporal_load(rp + lane);
        buf[nxt][r][1] = __builtin_nontemporal_load(rp + lane + 64);
        buf[nxt][r][2] = __builtin_nontemporal_load(rp + lane + 128);
      }
    }

    float p0 = dot4(buf[cur][0][0], qa) + dot4(buf[cur][0][1], qb)
             + dot4(buf[cur][0][2], qc);
    float p1 = dot4(buf[cur][1][0], qa) + dot4(buf[cur][1][1], qb)
             + dot4(buf[cur][1][2], qc);

    // Two interleaved 64-lane butterfly sums -> wave-uniform scores
    #pragma unroll
    for (int off = 32; off >= 1; off >>= 1) {
      p0 += __shfl_xor(p0, off, 64);
      p1 += __shfl_xor(p1, off, 64);
    }

    const float gm = fmaxf(p0, p1);
    if (gm > m) {                       // wave-uniform branch
      const float s = __expf(m - gm);   // exp(-inf)=0 on first group
      l *= s;
      oa *= s; ob *= s; oc *= s;
      m = gm;
    }
    const float e0 = __expf(p0 - m);
    const float e1 = __expf(p1 - m);
    l += e0 + e1;
    oa += e0 * buf[cur][0][0] + e1 * buf[cur][1][0];
    ob += e0 * buf[cur][0][1] + e1 * buf[cur][1][1];
    oc += e0 * buf[cur][0][2] + e1 * buf[cur][1][2];
  }

  // Combine the 4 wave partials in LDS
  __shared__ float s_o[NWAVES][HID];   // 12 KB
  __shared__ float s_m[NWAVES];
  __shared__ float s_l[NWAVES];
  f4v* so4 = reinterpret_cast<f4v*>(s_o[wave]);
  so4[lane]       = oa;
  so4[lane + 64]  = ob;
  so4[lane + 128] = oc;
  if (lane == 0) { s_m[wave] = m; s_l[wave] = l; }
  __syncthreads();

  const float mb = fmaxf(fmaxf(s_m[0], s_m[1]), fmaxf(s_m[2], s_m[3]));
  const float w0 = __expf(s_m[0] - mb);
  const float w1 = __expf(s_m[1] - mb);
  const float w2 = __expf(s_m[2] - mb);
  const float w3 = __expf(s_m[3] - mb);
  const float lsum = w0 * s_l[0] + w1 * s_l[1] + w2 * s_l[2] + w3 * s_l[3];

  const int pidx = b * CHUNKS + chunk;
  float* O = o_ws + (size_t)pidx * HID;
  #pragma unroll
  for (int j = 0; j < 3; ++j) {
    const int h = tid + 256 * j;
    O[h] = w0 * s_o[0][h] + w1 * s_o[1][h] + w2 * s_o[2][h] + w3 * s_o[3][h];
  }
  if (tid == 0) { m_ws[pidx] = mb; l_ws[pidx] = lsum; }
}

// Pass 2: one thread per output element. grid (BATCH, 6) x 128 threads.
// m/l loads are redundant per thread but fully L2-resident (8 KB total).
__global__ __launch_bounds__(128)
void attn_pass2(const float* __restrict__ m_ws,
                const float* __restrict__ l_ws,
                const float* __restrict__ o_ws,
                float* __restrict__ out) {
  const int b = blockIdx.x;
  const int h = blockIdx.y * 128 + threadIdx.x;

  float mg = -INFINITY;
  #pragma unroll 8
  for (int c = 0; c < CHUNKS; ++c)
    mg = fmaxf(mg, m_ws[b * CHUNKS + c]);

  float L = 0.0f;
  float acc = 0.0f;
  #pragma unroll 8
  for (int c = 0; c < CHUNKS; ++c) {
    const int pi = b * CHUNKS + c;
    const float a = __expf(m_ws[pi] - mg);
    L += a * l_ws[pi];
    acc += a * o_ws[(size_t)pi * HID + h];
  }
  out[(size_t)b * HID + h] = acc / L;
}

extern "C" void kernel_launch(void* const* d_in, const int* in_sizes, int n_in,
                              void* d_out, int out_size, void* d_ws, size_t ws_size,
                              hipStream_t stream) {
  const float* hidden = (const float*)d_in[0];   // [32, 4096, 768] fp32
  const float* q      = (const float*)d_in[1];   // [1, 768] fp32
  float* out = (float*)d_out;                    // [32, 768] fp32

  // Workspace layout: m[2048] | l[2048] | O[2048*768]  (~6.3 MB total)
  float* m_ws = (float*)d_ws;
  float* l_ws = m_ws + BATCH * CHUNKS;
  float* o_ws = l_ws + BATCH * CHUNKS;

  dim3 grid1(CHUNKS, BATCH);
  attn_pass1<<<grid1, 256, 0, stream>>>(hidden, q, m_ws, l_ws, o_ws);
  dim3 grid2(BATCH, HID / 128);
  attn_pass2<<<grid2, 128, 0, stream>>>(m_ws, l_ws, o_ws, out);
}